// Round 4
// baseline (1751.875 us; speedup 1.0000x reference)
//
#include <hip/hip_runtime.h>
#include <hip/hip_bf16.h>

typedef __hip_bfloat16 bf16;

__device__ __forceinline__ void storeOut(float* p, float v) { *p = v; }
__device__ __forceinline__ void storeOut(bf16* p, float v) { *p = __float2bfloat16(v); }

constexpr int B_ = 4, T_ = 1024, M_ = 256, C_ = 512, H_ = 8, HD_ = 64, C3_ = 1536;

// ---------------- generic tiled GEMM: C = A(MxK) @ W(KxN) + bias ----------------
// 64x64 tile, 16 k-slab, 256 threads, 4x4 per thread. LDS rows padded to 68.
template <typename OT>
__global__ __launch_bounds__(256) void gemm_bias_kernel(
    const float* __restrict__ A, const float* __restrict__ W, const float* __restrict__ bias,
    OT* __restrict__ Cmat, int Mrows, int N, int K)
{
    __shared__ float As[16][68];  // [k][m]
    __shared__ float Bs[16][68];  // [k][n]
    const int tid = threadIdx.x;
    const int tx = tid & 15, ty = tid >> 4;
    const int n0 = blockIdx.x * 64, m0 = blockIdx.y * 64;
    float acc[4][4] = {};
    for (int k0 = 0; k0 < K; k0 += 16) {
        #pragma unroll
        for (int idx = tid; idx < 1024; idx += 256) {
            int r = idx >> 4, c = idx & 15;
            As[c][r] = A[(size_t)(m0 + r) * K + (k0 + c)];
            int br = idx >> 6, bc = idx & 63;
            Bs[br][bc] = W[(size_t)(k0 + br) * N + (n0 + bc)];
        }
        __syncthreads();
        #pragma unroll
        for (int kk = 0; kk < 16; ++kk) {
            float4 a4 = *(const float4*)&As[kk][ty * 4];
            float4 b4 = *(const float4*)&Bs[kk][tx * 4];
            float a[4] = {a4.x, a4.y, a4.z, a4.w};
            float b[4] = {b4.x, b4.y, b4.z, b4.w};
            #pragma unroll
            for (int i = 0; i < 4; ++i)
                #pragma unroll
                for (int j = 0; j < 4; ++j)
                    acc[i][j] = fmaf(a[i], b[j], acc[i][j]);
        }
        __syncthreads();
    }
    #pragma unroll
    for (int i = 0; i < 4; ++i) {
        int row = m0 + ty * 4 + i;
        #pragma unroll
        for (int j = 0; j < 4; ++j) {
            int col = n0 + tx * 4 + j;
            storeOut(&Cmat[(size_t)row * N + col], acc[i][j] + bias[col]);
        }
    }
}

// ---------------- catt1 / catt2: per-(b,h,row) dot of 64 ----------------
__global__ __launch_bounds__(256) void catt12_kernel(
    const float* __restrict__ qkv, const float* __restrict__ w4,
    float* __restrict__ out, int Nrows)
{
    int i = blockIdx.x * 256 + threadIdx.x;   // i = bh*Nrows + row  (grid sized exactly)
    int bh = i / Nrows, t = i - bh * Nrows;
    int b = bh >> 3, h = bh & 7;
    const float* row = qkv + (size_t)(b * Nrows + t) * C3_ + h * HD_;  // q part (offset 0)
    const float* w = w4 + h * HD_;
    float s = 0.f;
    #pragma unroll
    for (int d = 0; d < HD_; ++d) s = fmaf(row[d], w[d], s);
    out[i] = s;
}

// ---------------- catt = catt1 + catt2 + 0.125 * (qx*w4xy) @ ky^T ----------------
__global__ __launch_bounds__(256) void catt3_kernel(
    const float* __restrict__ qkv_x, const float* __restrict__ qkv_y,
    const float* __restrict__ w4xy, const float* __restrict__ catt1,
    const float* __restrict__ catt2, float* __restrict__ catt)
{
    __shared__ float As[64][68];  // [t][d] = qx * w4xy
    __shared__ float Bs[64][65];  // [d][m] = ky^T
    __shared__ float w4s[64];
    const int tid = threadIdx.x;
    const int bh = blockIdx.z, b = bh >> 3, h = bh & 7;
    const int t0 = blockIdx.y * 64, m0 = blockIdx.x * 64;
    if (tid < 64) w4s[tid] = w4xy[h * HD_ + tid];
    __syncthreads();
    for (int idx = tid; idx < 4096; idx += 256) {
        int rr = idx >> 6, dd = idx & 63;
        As[rr][dd] = qkv_x[(size_t)(b * T_ + t0 + rr) * C3_ + h * HD_ + dd] * w4s[dd];
        Bs[dd][rr] = qkv_y[(size_t)(b * M_ + m0 + rr) * C3_ + C_ + h * HD_ + dd];
    }
    __syncthreads();
    const int tx = tid & 15, ty = tid >> 4;
    float acc[4][4] = {};
    for (int d = 0; d < 64; ++d) {
        float a[4], bb[4];
        #pragma unroll
        for (int i = 0; i < 4; ++i) a[i] = As[ty * 4 + i][d];
        #pragma unroll
        for (int j = 0; j < 4; ++j) bb[j] = Bs[d][tx * 4 + j];
        #pragma unroll
        for (int i = 0; i < 4; ++i)
            #pragma unroll
            for (int j = 0; j < 4; ++j)
                acc[i][j] = fmaf(a[i], bb[j], acc[i][j]);
    }
    #pragma unroll
    for (int i = 0; i < 4; ++i) {
        int t = t0 + ty * 4 + i;
        float c1 = catt1[bh * T_ + t];
        #pragma unroll
        for (int j = 0; j < 4; ++j) {
            int m = m0 + tx * 4 + j;
            catt[((size_t)bh * T_ + t) * M_ + m] = acc[i][j] * 0.125f + c1 + catt2[bh * M_ + m];
        }
    }
}

// ---------------- softmax over t (axis=-2): one block per bh, thread per m ----------------
__global__ __launch_bounds__(256) void col_softmax_kernel(
    const float* __restrict__ catt, float* __restrict__ catt_y2x)
{
    const int bh = blockIdx.x, m = threadIdx.x;
    const float* p = catt + (size_t)bh * T_ * M_ + m;
    float mx = -INFINITY;
    for (int t = 0; t < T_; ++t) mx = fmaxf(mx, p[t * M_]);
    float s = 0.f;
    for (int t = 0; t < T_; ++t) s += __expf(p[t * M_] - mx);
    float inv = 1.f / s;
    float* o = catt_y2x + (size_t)bh * T_ * M_ + m;
    for (int t = 0; t < T_; ++t) o[t * M_] = __expf(p[t * M_] - mx) * inv;
}

// ---------------- softmax over m (axis=-1), in place: one block per row ----------------
__global__ __launch_bounds__(256) void row_softmax_kernel(float* __restrict__ catt)
{
    const int row = blockIdx.x;   // B*H*T rows of length 256
    const int tid = threadIdx.x;
    float v = catt[(size_t)row * M_ + tid];
    float mx = v;
    for (int off = 1; off < 64; off <<= 1) mx = fmaxf(mx, __shfl_xor(mx, off));
    __shared__ float red[4], red2[4];
    if ((tid & 63) == 0) red[tid >> 6] = mx;
    __syncthreads();
    mx = fmaxf(fmaxf(red[0], red[1]), fmaxf(red[2], red[3]));
    float e = __expf(v - mx);
    float s = e;
    for (int off = 1; off < 64; off <<= 1) s += __shfl_xor(s, off);
    if ((tid & 63) == 0) red2[tid >> 6] = s;
    __syncthreads();
    s = red2[0] + red2[1] + red2[2] + red2[3];
    catt[(size_t)row * M_ + tid] = e / s;
}

// ---------------- cval = x + catt_x2y @ v_y ----------------
__global__ __launch_bounds__(256) void cval_x2y_kernel(
    const float* __restrict__ catt_x2y, const float* __restrict__ qkv_y,
    const float* __restrict__ x, float* __restrict__ cval)
{
    __shared__ float As[16][68];  // [k(m)][t]
    __shared__ float Bs[16][68];  // [k(m)][d]
    const int tid = threadIdx.x;
    const int bh = blockIdx.y, b = bh >> 3, h = bh & 7;
    const int t0 = blockIdx.x * 64;
    const int tx = tid & 15, ty = tid >> 4;
    float acc[4][4] = {};
    for (int k0 = 0; k0 < M_; k0 += 16) {
        #pragma unroll
        for (int idx = tid; idx < 1024; idx += 256) {
            int r = idx >> 4, c = idx & 15;
            As[c][r] = catt_x2y[((size_t)bh * T_ + t0 + r) * M_ + (k0 + c)];
            int br = idx >> 6, bc = idx & 63;
            Bs[br][bc] = qkv_y[(size_t)(b * M_ + k0 + br) * C3_ + 2 * C_ + h * HD_ + bc];
        }
        __syncthreads();
        #pragma unroll
        for (int kk = 0; kk < 16; ++kk) {
            float4 a4 = *(const float4*)&As[kk][ty * 4];
            float4 b4 = *(const float4*)&Bs[kk][tx * 4];
            float a[4] = {a4.x, a4.y, a4.z, a4.w};
            float b[4] = {b4.x, b4.y, b4.z, b4.w};
            #pragma unroll
            for (int i = 0; i < 4; ++i)
                #pragma unroll
                for (int j = 0; j < 4; ++j)
                    acc[i][j] = fmaf(a[i], b[j], acc[i][j]);
        }
        __syncthreads();
    }
    #pragma unroll
    for (int i = 0; i < 4; ++i) {
        int t = t0 + ty * 4 + i;
        #pragma unroll
        for (int j = 0; j < 4; ++j) {
            int d = tx * 4 + j;
            size_t idx = (size_t)(b * T_ + t) * C_ + h * HD_ + d;
            cval[idx] = acc[i][j] + x[idx];
        }
    }
}

// ---------------- flash attention (causal, online softmax) ----------------
// MODE 0: chain — Q=catt_x2y, K=catt_y2x (DK=256), V=v_x, out += cval
// MODE 1: self  — Q=q_x, K=k_x (DK=64), V=v_x, out -> sval
template <int MODE>
__global__ __launch_bounds__(256) void flash_kernel(
    const float* __restrict__ Qm, const float* __restrict__ Km,
    const float* __restrict__ qkv_x, float scale, float* __restrict__ outbuf)
{
    constexpr int DK = (MODE == 0) ? 256 : 64;
    __shared__ float Qs[32][DK + 4];
    __shared__ float Ks[16][DK + 4];
    __shared__ float Vs[16][68];
    const int tid = threadIdx.x;
    const int bh = blockIdx.y, b = bh >> 3, h = bh & 7;
    const int t0 = blockIdx.x * 32;
    const int r = tid >> 3, c = tid & 7;

    for (int idx = tid; idx < 32 * DK; idx += 256) {
        int rr = idx / DK, kk = idx % DK;
        float qv;
        if constexpr (MODE == 0)
            qv = Qm[((size_t)bh * T_ + t0 + rr) * M_ + kk];
        else
            qv = qkv_x[(size_t)(b * T_ + t0 + rr) * C3_ + h * HD_ + kk];
        Qs[rr][kk] = qv;
    }
    __syncthreads();

    float m_i = -INFINITY, l_i = 0.f;
    float acc[8];
    #pragma unroll
    for (int j = 0; j < 8; ++j) acc[j] = 0.f;

    const int nst = (t0 + 32) >> 4;
    for (int st = 0; st < nst; ++st) {
        const int s0 = st * 16;
        for (int idx = tid; idx < 16 * DK; idx += 256) {
            int rr = idx / DK, kk = idx % DK;
            float kv;
            if constexpr (MODE == 0)
                kv = Km[((size_t)bh * T_ + s0 + rr) * M_ + kk];
            else
                kv = qkv_x[(size_t)(b * T_ + s0 + rr) * C3_ + C_ + h * HD_ + kk];
            Ks[rr][kk] = kv;
        }
        for (int idx = tid; idx < 16 * 64; idx += 256) {
            int rr = idx >> 6, dd = idx & 63;
            Vs[rr][dd] = qkv_x[(size_t)(b * T_ + s0 + rr) * C3_ + 2 * C_ + h * HD_ + dd];
        }
        __syncthreads();

        float sc0 = 0.f, sc1 = 0.f;
        #pragma unroll
        for (int k = 0; k < DK; k += 4) {
            float4 q  = *(const float4*)&Qs[r][k];
            float4 ka = *(const float4*)&Ks[c][k];
            float4 kb = *(const float4*)&Ks[c + 8][k];
            sc0 = fmaf(q.x, ka.x, sc0); sc0 = fmaf(q.y, ka.y, sc0);
            sc0 = fmaf(q.z, ka.z, sc0); sc0 = fmaf(q.w, ka.w, sc0);
            sc1 = fmaf(q.x, kb.x, sc1); sc1 = fmaf(q.y, kb.y, sc1);
            sc1 = fmaf(q.z, kb.z, sc1); sc1 = fmaf(q.w, kb.w, sc1);
        }
        const int t = t0 + r;
        sc0 = (s0 + c     <= t) ? sc0 * scale : -1e30f;
        sc1 = (s0 + c + 8 <= t) ? sc1 * scale : -1e30f;
        float mt = fmaxf(sc0, sc1);
        mt = fmaxf(mt, __shfl_xor(mt, 1));
        mt = fmaxf(mt, __shfl_xor(mt, 2));
        mt = fmaxf(mt, __shfl_xor(mt, 4));
        float m_new = fmaxf(m_i, mt);
        float p0 = __expf(sc0 - m_new);
        float p1 = __expf(sc1 - m_new);
        float ps = p0 + p1;
        ps += __shfl_xor(ps, 1);
        ps += __shfl_xor(ps, 2);
        ps += __shfl_xor(ps, 4);
        float alpha = __expf(m_i - m_new);
        l_i = l_i * alpha + ps;
        m_i = m_new;
        #pragma unroll
        for (int j = 0; j < 8; ++j) acc[j] *= alpha;
        const int wbase = (tid & 63) & ~7;
        #pragma unroll
        for (int s = 0; s < 16; ++s) {
            float pv = (s < 8) ? __shfl(p0, wbase + s) : __shfl(p1, wbase + (s - 8));
            float4 v0 = *(const float4*)&Vs[s][c * 8];
            float4 v1 = *(const float4*)&Vs[s][c * 8 + 4];
            acc[0] = fmaf(pv, v0.x, acc[0]);
            acc[1] = fmaf(pv, v0.y, acc[1]);
            acc[2] = fmaf(pv, v0.z, acc[2]);
            acc[3] = fmaf(pv, v0.w, acc[3]);
            acc[4] = fmaf(pv, v1.x, acc[4]);
            acc[5] = fmaf(pv, v1.y, acc[5]);
            acc[6] = fmaf(pv, v1.z, acc[6]);
            acc[7] = fmaf(pv, v1.w, acc[7]);
        }
        __syncthreads();
    }
    const float inv = 1.f / l_i;
    const int t = t0 + r;
    size_t obase = (size_t)(b * T_ + t) * C_ + h * HD_ + c * 8;
    #pragma unroll
    for (int j = 0; j < 8; ++j) {
        float v = acc[j] * inv;
        if constexpr (MODE == 0) outbuf[obase + j] += v;
        else                     outbuf[obase + j] = v;
    }
}

// ---------------- gating elementwise ----------------
__global__ __launch_bounds__(256) void gate_kernel(
    const float* __restrict__ gs_lin, const float* __restrict__ gc_lin,
    const float* __restrict__ cval, const float* __restrict__ sval,
    float* __restrict__ gated)
{
    int i = blockIdx.x * 256 + threadIdx.x;   // grid sized exactly B*T*C
    float sg = 1.f / (1.f + __expf(-gs_lin[i]));
    float cg = 1.f / (1.f + __expf(-gc_lin[i]));
    gated[i] = sg * cval[i] + cg * sval[i];
}

extern "C" void kernel_launch(void* const* d_in, const int* in_sizes, int n_in,
                              void* d_out, int out_size, void* d_ws, size_t ws_size,
                              hipStream_t stream)
{
    // Reference declares every tensor float32 -> inputs fp32 AND output fp32.
    const float* x      = (const float*)d_in[0];
    const float* y      = (const float*)d_in[1];
    // d_in[2]: attn_x_mask — structurally causal tril, computed inline instead
    const float* Wqkv_x = (const float*)d_in[3];
    const float* bqkv_x = (const float*)d_in[4];
    const float* Wqkv_y = (const float*)d_in[5];
    const float* bqkv_y = (const float*)d_in[6];
    const float* w4x    = (const float*)d_in[7];
    const float* w4y    = (const float*)d_in[8];
    const float* w4xy   = (const float*)d_in[9];
    const float* Wgs    = (const float*)d_in[10];
    const float* bgs    = (const float*)d_in[11];
    const float* Wgc    = (const float*)d_in[12];
    const float* bgc    = (const float*)d_in[13];
    const float* Wp     = (const float*)d_in[14];
    const float* bp     = (const float*)d_in[15];

    float* ws = (float*)d_ws;
    float* qkv_x  = ws;                 //  6,291,456 f  (B*T,3C)
    float* qkv_y  = ws +  6291456;      //  1,572,864 f  (B*M,3C)
    float* catt   = ws +  7864320;      //  8,388,608 f  (B,H,T,M) -> catt_x2y in place
    float* caty2x = ws + 16252928;      //  8,388,608 f
    float* cval   = ws + 24641536;      //  2,097,152 f
    float* sval   = ws + 26738688;      //  2,097,152 f
    float* catt1b = ws + 28835840;      //     32,768 f
    float* catt2b = ws + 28868608;      //      8,192 f   (total 115.5 MB)
    float* gs_lin = qkv_x;              // reuse: qkv_x dead after flash kernels
    float* gc_lin = qkv_x + 2097152;
    float* gated  = qkv_x + 4194304;

    // 1-2: QKV projections
    gemm_bias_kernel<float><<<dim3(24, 64), 256, 0, stream>>>(
        x, Wqkv_x, bqkv_x, qkv_x, B_ * T_, C3_, C_);
    gemm_bias_kernel<float><<<dim3(24, 16), 256, 0, stream>>>(
        y, Wqkv_y, bqkv_y, qkv_y, B_ * M_, C3_, C_);

    // 3-5: additive-bias attention logits catt (B,H,T,M)
    catt12_kernel<<<128, 256, 0, stream>>>(qkv_x, w4x, catt1b, T_);
    catt12_kernel<<<32, 256, 0, stream>>>(qkv_y, w4y, catt2b, M_);
    catt3_kernel<<<dim3(4, 16, 32), 256, 0, stream>>>(qkv_x, qkv_y, w4xy, catt1b, catt2b, catt);

    // 6-7: the two softmaxes (column first — row softmax is in place)
    col_softmax_kernel<<<32, 256, 0, stream>>>(catt, caty2x);
    row_softmax_kernel<<<32768, 256, 0, stream>>>(catt);

    // 8: cval = x + catt_x2y @ v_y
    cval_x2y_kernel<<<dim3(16, 32), 256, 0, stream>>>(catt, qkv_y, x, cval);

    // 9: cval += softmax(causal(catt_x2y @ catt_y2x^T / sqrt(M))) @ v_x
    flash_kernel<0><<<dim3(32, 32), 256, 0, stream>>>(catt, caty2x, qkv_x, 1.f / 16.f, cval);

    // 10: sval = causal self-attention(q_x, k_x, v_x)
    flash_kernel<1><<<dim3(32, 32), 256, 0, stream>>>(nullptr, nullptr, qkv_x, 0.125f, sval);

    // 11-14: gates and output projection
    gemm_bias_kernel<float><<<dim3(8, 64), 256, 0, stream>>>(
        sval, Wgs, bgs, gs_lin, B_ * T_, C_, C_);
    gemm_bias_kernel<float><<<dim3(8, 64), 256, 0, stream>>>(
        cval, Wgc, bgc, gc_lin, B_ * T_, C_, C_);
    gate_kernel<<<8192, 256, 0, stream>>>(gs_lin, gc_lin, cval, sval, gated);
    // OUTPUT IS FP32 (reference output dtype) — R2's only bug was writing bf16 here.
    gemm_bias_kernel<float><<<dim3(8, 64), 256, 0, stream>>>(
        gated, Wp, bp, (float*)d_out, B_ * T_, C_, C_);
}

// Round 5
// 703.576 us; speedup vs baseline: 2.4900x; 2.4900x over previous
//
#include <hip/hip_runtime.h>
#include <hip/hip_bf16.h>

typedef __hip_bfloat16 bf16;
using f4 = __attribute__((ext_vector_type(4))) float;
using s8 = __attribute__((ext_vector_type(8))) short;

__device__ __forceinline__ void storeOut(float* p, float v) { *p = v; }
__device__ __forceinline__ void storeOut(bf16* p, float v) { *p = __float2bfloat16(v); }
__device__ __forceinline__ short bfs(float x) { return __builtin_bit_cast(short, __float2bfloat16(x)); }
__device__ __forceinline__ void pack8(short* dst, const float* sp) {
    s8 r;
    #pragma unroll
    for (int j = 0; j < 8; ++j) r[j] = bfs(sp[j]);
    *(s8*)dst = r;
}

constexpr int B_ = 4, T_ = 1024, M_ = 256, C_ = 512, H_ = 8, HD_ = 64, C3_ = 1536;

// ---------------- generic tiled GEMM: C = A(MxK) @ W(KxN) + bias ----------------
template <typename OT>
__global__ __launch_bounds__(256) void gemm_bias_kernel(
    const float* __restrict__ A, const float* __restrict__ W, const float* __restrict__ bias,
    OT* __restrict__ Cmat, int N, int K)
{
    __shared__ float As[16][68];  // [k][m]
    __shared__ float Bs[16][68];  // [k][n]
    const int tid = threadIdx.x;
    const int tx = tid & 15, ty = tid >> 4;
    const int n0 = blockIdx.x * 64, m0 = blockIdx.y * 64;
    float acc[4][4] = {};
    for (int k0 = 0; k0 < K; k0 += 16) {
        #pragma unroll
        for (int idx = tid; idx < 1024; idx += 256) {
            int r = idx >> 4, c = idx & 15;
            As[c][r] = A[(size_t)(m0 + r) * K + (k0 + c)];
            int br = idx >> 6, bc = idx & 63;
            Bs[br][bc] = W[(size_t)(k0 + br) * N + (n0 + bc)];
        }
        __syncthreads();
        #pragma unroll
        for (int kk = 0; kk < 16; ++kk) {
            float4 a4 = *(const float4*)&As[kk][ty * 4];
            float4 b4 = *(const float4*)&Bs[kk][tx * 4];
            float a[4] = {a4.x, a4.y, a4.z, a4.w};
            float b[4] = {b4.x, b4.y, b4.z, b4.w};
            #pragma unroll
            for (int i = 0; i < 4; ++i)
                #pragma unroll
                for (int j = 0; j < 4; ++j)
                    acc[i][j] = fmaf(a[i], b[j], acc[i][j]);
        }
        __syncthreads();
    }
    #pragma unroll
    for (int i = 0; i < 4; ++i) {
        int row = m0 + ty * 4 + i;
        #pragma unroll
        for (int j = 0; j < 4; ++j) {
            int col = n0 + tx * 4 + j;
            storeOut(&Cmat[(size_t)row * N + col], acc[i][j] + bias[col]);
        }
    }
}

// ---------------- catt1 / catt2 ----------------
__global__ __launch_bounds__(256) void catt12_kernel(
    const float* __restrict__ qkv, const float* __restrict__ w4,
    float* __restrict__ out, int Nrows)
{
    int i = blockIdx.x * 256 + threadIdx.x;
    int bh = i / Nrows, t = i - bh * Nrows;
    int b = bh >> 3, h = bh & 7;
    const float* row = qkv + (size_t)(b * Nrows + t) * C3_ + h * HD_;
    const float* w = w4 + h * HD_;
    float s = 0.f;
    #pragma unroll
    for (int d = 0; d < HD_; ++d) s = fmaf(row[d], w[d], s);
    out[i] = s;
}

// ---------------- catt = catt1 + catt2 + 0.125 * (qx*w4xy) @ ky^T ----------------
__global__ __launch_bounds__(256) void catt3_kernel(
    const float* __restrict__ qkv_x, const float* __restrict__ qkv_y,
    const float* __restrict__ w4xy, const float* __restrict__ catt1,
    const float* __restrict__ catt2, float* __restrict__ catt)
{
    __shared__ float As[64][68];
    __shared__ float Bs[64][65];
    __shared__ float w4s[64];
    const int tid = threadIdx.x;
    const int bh = blockIdx.z, b = bh >> 3, h = bh & 7;
    const int t0 = blockIdx.y * 64, m0 = blockIdx.x * 64;
    if (tid < 64) w4s[tid] = w4xy[h * HD_ + tid];
    __syncthreads();
    for (int idx = tid; idx < 4096; idx += 256) {
        int rr = idx >> 6, dd = idx & 63;
        As[rr][dd] = qkv_x[(size_t)(b * T_ + t0 + rr) * C3_ + h * HD_ + dd] * w4s[dd];
        Bs[dd][rr] = qkv_y[(size_t)(b * M_ + m0 + rr) * C3_ + C_ + h * HD_ + dd];
    }
    __syncthreads();
    const int tx = tid & 15, ty = tid >> 4;
    float acc[4][4] = {};
    for (int d = 0; d < 64; ++d) {
        float a[4], bb[4];
        #pragma unroll
        for (int i = 0; i < 4; ++i) a[i] = As[ty * 4 + i][d];
        #pragma unroll
        for (int j = 0; j < 4; ++j) bb[j] = Bs[d][tx * 4 + j];
        #pragma unroll
        for (int i = 0; i < 4; ++i)
            #pragma unroll
            for (int j = 0; j < 4; ++j)
                acc[i][j] = fmaf(a[i], bb[j], acc[i][j]);
    }
    #pragma unroll
    for (int i = 0; i < 4; ++i) {
        int t = t0 + ty * 4 + i;
        float c1 = catt1[bh * T_ + t];
        #pragma unroll
        for (int j = 0; j < 4; ++j) {
            int m = m0 + tx * 4 + j;
            catt[((size_t)bh * T_ + t) * M_ + m] = acc[i][j] * 0.125f + c1 + catt2[bh * M_ + m];
        }
    }
}

// ---------------- col softmax stage 1: per-(bh,chunk,m) online max/sumexp ----------------
__global__ __launch_bounds__(256) void colpart_kernel(
    const float* __restrict__ catt, float* __restrict__ pmax, float* __restrict__ psum)
{
    const int ch = blockIdx.x, bh = blockIdx.y, m = threadIdx.x;
    const float* p = catt + ((size_t)bh * T_ + ch * 64) * M_ + m;
    float mx = -3e38f, s = 0.f;
    for (int t = 0; t < 64; ++t) {
        float v = p[t * M_];
        if (v > mx) { s = s * __expf(mx - v) + 1.f; mx = v; }
        else s += __expf(v - mx);
    }
    pmax[(bh * 16 + ch) * M_ + m] = mx;
    psum[(bh * 16 + ch) * M_ + m] = s;
}

// ---------------- col softmax stage 2: combine 16 partials ----------------
__global__ __launch_bounds__(256) void colfin_kernel(
    const float* __restrict__ pmax, const float* __restrict__ psum,
    float* __restrict__ colmax, float* __restrict__ colinv)
{
    const int bh = blockIdx.x, m = threadIdx.x;
    float mx = -3e38f;
    #pragma unroll
    for (int ch = 0; ch < 16; ++ch) mx = fmaxf(mx, pmax[(bh * 16 + ch) * M_ + m]);
    float s = 0.f;
    #pragma unroll
    for (int ch = 0; ch < 16; ++ch)
        s += psum[(bh * 16 + ch) * M_ + m] * __expf(pmax[(bh * 16 + ch) * M_ + m] - mx);
    colmax[bh * M_ + m] = mx;
    colinv[bh * M_ + m] = 1.f / s;
}

// ---------------- col softmax stage 3: write y2x bf16 ----------------
__global__ __launch_bounds__(256) void y2x_write_kernel(
    const float* __restrict__ catt, const float* __restrict__ colmax,
    const float* __restrict__ colinv, bf16* __restrict__ y2x)
{
    const int ch = blockIdx.x, bh = blockIdx.y, m = threadIdx.x;
    const float mx = colmax[bh * M_ + m], inv = colinv[bh * M_ + m];
    const size_t base = ((size_t)bh * T_ + ch * 64) * M_ + m;
    for (int t = 0; t < 64; ++t)
        y2x[base + t * M_] = __float2bfloat16(__expf(catt[base + t * M_] - mx) * inv);
}

// ---------------- row softmax (in-place fp32) + bf16 copy ----------------
__global__ __launch_bounds__(256) void row_softmax_kernel(
    float* __restrict__ catt, bf16* __restrict__ x2y_bf)
{
    const int row = blockIdx.x;
    const int tid = threadIdx.x;
    float v = catt[(size_t)row * M_ + tid];
    float mx = v;
    for (int off = 1; off < 64; off <<= 1) mx = fmaxf(mx, __shfl_xor(mx, off));
    __shared__ float red[4], red2[4];
    if ((tid & 63) == 0) red[tid >> 6] = mx;
    __syncthreads();
    mx = fmaxf(fmaxf(red[0], red[1]), fmaxf(red[2], red[3]));
    float e = __expf(v - mx);
    float s = e;
    for (int off = 1; off < 64; off <<= 1) s += __shfl_xor(s, off);
    if ((tid & 63) == 0) red2[tid >> 6] = s;
    __syncthreads();
    s = red2[0] + red2[1] + red2[2] + red2[3];
    float p = e / s;
    catt[(size_t)row * M_ + tid] = p;
    x2y_bf[(size_t)row * M_ + tid] = __float2bfloat16(p);
}

// ---------------- cval = x + catt_x2y @ v_y ----------------
__global__ __launch_bounds__(256) void cval_x2y_kernel(
    const float* __restrict__ catt_x2y, const float* __restrict__ qkv_y,
    const float* __restrict__ x, float* __restrict__ cval)
{
    __shared__ float As[16][68];
    __shared__ float Bs[16][68];
    const int tid = threadIdx.x;
    const int bh = blockIdx.y, b = bh >> 3, h = bh & 7;
    const int t0 = blockIdx.x * 64;
    const int tx = tid & 15, ty = tid >> 4;
    float acc[4][4] = {};
    for (int k0 = 0; k0 < M_; k0 += 16) {
        #pragma unroll
        for (int idx = tid; idx < 1024; idx += 256) {
            int r = idx >> 4, c = idx & 15;
            As[c][r] = catt_x2y[((size_t)bh * T_ + t0 + r) * M_ + (k0 + c)];
            int br = idx >> 6, bc = idx & 63;
            Bs[br][bc] = qkv_y[(size_t)(b * M_ + k0 + br) * C3_ + 2 * C_ + h * HD_ + bc];
        }
        __syncthreads();
        #pragma unroll
        for (int kk = 0; kk < 16; ++kk) {
            float4 a4 = *(const float4*)&As[kk][ty * 4];
            float4 b4 = *(const float4*)&Bs[kk][tx * 4];
            float a[4] = {a4.x, a4.y, a4.z, a4.w};
            float b[4] = {b4.x, b4.y, b4.z, b4.w};
            #pragma unroll
            for (int i = 0; i < 4; ++i)
                #pragma unroll
                for (int j = 0; j < 4; ++j)
                    acc[i][j] = fmaf(a[i], b[j], acc[i][j]);
        }
        __syncthreads();
    }
    #pragma unroll
    for (int i = 0; i < 4; ++i) {
        int t = t0 + ty * 4 + i;
        #pragma unroll
        for (int j = 0; j < 4; ++j) {
            int d = tx * 4 + j;
            size_t idx = (size_t)(b * T_ + t) * C_ + h * HD_ + d;
            cval[idx] = acc[i][j] + x[idx];
        }
    }
}

// ---------------- MFMA flash attention (causal, online softmax) ----------------
// MODE 0: chain — Q=x2y(bf16), K=y2x(bf16), DK=256, V=v_x, out += cval
// MODE 1: self  — Q=q_x, K=k_x (fp32->bf16), DK=64, V=v_x, out = sval
// Block: 256 thr = 4 waves; Q tile 64 rows (16/wave), key tile 64, K chunked 64-k.
// MFMA 16x16x32 bf16. Layouts (m89/m120): C/D col=lane&15,row=quad*4+reg;
// A/B frag: idx=lane&15, k=quad*8+j. LDS rows padded +8 bf16 (16B) -> frag
// reads shift 4 banks/row: conflict-free.
template <int MODE>
__global__ __launch_bounds__(256) void flash_mfma_kernel(
    const bf16* __restrict__ Qsrc, const bf16* __restrict__ Ksrc,
    const float* __restrict__ qkv_x, float scale, float* __restrict__ outbuf)
{
    constexpr int DK = (MODE == 0) ? 256 : 64;
    constexpr int NCH = DK / 64;
    __shared__ short Qs[64][DK + 8];
    __shared__ short Ks[64][72];
    __shared__ short Vt[64][72];   // V transposed: [d][s]
    __shared__ short Ps[4][16][72];
    const int tid = threadIdx.x;
    const int wave = tid >> 6, lane = tid & 63;
    const int quad = lane >> 4, l16 = lane & 15;
    const int bh = blockIdx.y, b = bh >> 3, h = bh & 7;
    const int t0 = blockIdx.x * 64;

    // stage Q tile (64 x DK) as bf16
    for (int i = tid; i < 64 * (DK / 8); i += 256) {
        int row = i / (DK / 8), cg = i % (DK / 8);
        if constexpr (MODE == 0)
            *(s8*)&Qs[row][cg * 8] = *(const s8*)&Qsrc[((size_t)bh * T_ + t0 + row) * M_ + cg * 8];
        else
            pack8(&Qs[row][cg * 8], &qkv_x[(size_t)(b * T_ + t0 + row) * C3_ + h * HD_ + cg * 8]);
    }

    float m_i[4], l_i[4];
    f4 o[4];
    #pragma unroll
    for (int r = 0; r < 4; ++r) { m_i[r] = -3e38f; l_i[r] = 0.f; o[r] = (f4)0.f; }

    const int nst = blockIdx.x + 1;
    for (int st = 0; st < nst; ++st) {
        const int s0 = st * 64;
        __syncthreads();   // prior-tile reads of Ks/Vt/Qs-stage done
        // stage V^T (64 s x 64 d -> Vt[d][s])
        {
            int s = tid >> 4, d4 = (tid & 15) * 4;
            #pragma unroll
            for (int it = 0; it < 4; ++it, s += 16) {
                float4 v = *(const float4*)&qkv_x[(size_t)(b * T_ + s0 + s) * C3_ + 2 * C_ + h * HD_ + d4];
                Vt[d4 + 0][s] = bfs(v.x); Vt[d4 + 1][s] = bfs(v.y);
                Vt[d4 + 2][s] = bfs(v.z); Vt[d4 + 3][s] = bfs(v.w);
            }
        }
        f4 sc[4];
        #pragma unroll
        for (int nt = 0; nt < 4; ++nt) sc[nt] = (f4)0.f;
        for (int kc = 0; kc < NCH; ++kc) {
            if (kc > 0) __syncthreads();   // protect Ks reuse across chunks
            for (int i = tid; i < 512; i += 256) {
                int key = i >> 3, cg = i & 7;
                if constexpr (MODE == 0)
                    *(s8*)&Ks[key][cg * 8] =
                        *(const s8*)&Ksrc[((size_t)bh * T_ + s0 + key) * M_ + kc * 64 + cg * 8];
                else
                    pack8(&Ks[key][cg * 8],
                          &qkv_x[(size_t)(b * T_ + s0 + key) * C3_ + C_ + h * HD_ + cg * 8]);
            }
            __syncthreads();
            #pragma unroll
            for (int ks = 0; ks < 2; ++ks) {
                s8 a = *(const s8*)&Qs[wave * 16 + l16][kc * 64 + ks * 32 + quad * 8];
                #pragma unroll
                for (int nt = 0; nt < 4; ++nt) {
                    s8 bf = *(const s8*)&Ks[nt * 16 + l16][ks * 32 + quad * 8];
                    sc[nt] = __builtin_amdgcn_mfma_f32_16x16x32_bf16(a, bf, sc[nt], 0, 0, 0);
                }
            }
        }
        // online softmax per row (4 rows/lane, cols spread over 16 lanes of quad)
        #pragma unroll
        for (int reg = 0; reg < 4; ++reg) {
            const int t_g = t0 + wave * 16 + quad * 4 + reg;
            float mx = -3e38f;
            #pragma unroll
            for (int nt = 0; nt < 4; ++nt) {
                float v = (s0 + nt * 16 + l16 <= t_g) ? sc[nt][reg] * scale : -3e38f;
                sc[nt][reg] = v;
                mx = fmaxf(mx, v);
            }
            mx = fmaxf(mx, __shfl_xor(mx, 1));
            mx = fmaxf(mx, __shfl_xor(mx, 2));
            mx = fmaxf(mx, __shfl_xor(mx, 4));
            mx = fmaxf(mx, __shfl_xor(mx, 8));
            float mnew = fmaxf(m_i[reg], mx);
            float sum = 0.f;
            #pragma unroll
            for (int nt = 0; nt < 4; ++nt) {
                float p = __expf(sc[nt][reg] - mnew);
                sc[nt][reg] = p;
                sum += p;
            }
            sum += __shfl_xor(sum, 1);
            sum += __shfl_xor(sum, 2);
            sum += __shfl_xor(sum, 4);
            sum += __shfl_xor(sum, 8);
            float alpha = __expf(m_i[reg] - mnew);
            l_i[reg] = l_i[reg] * alpha + sum;
            m_i[reg] = mnew;
            #pragma unroll
            for (int dt = 0; dt < 4; ++dt) o[dt][reg] *= alpha;
            #pragma unroll
            for (int nt = 0; nt < 4; ++nt)
                Ps[wave][quad * 4 + reg][nt * 16 + l16] = bfs(sc[nt][reg]);
        }
        // PV: o[dt] += P(16x64) @ V(64x16dt)   (Ps private per wave; lgkmcnt ordering)
        #pragma unroll
        for (int ks = 0; ks < 2; ++ks) {
            s8 a = *(const s8*)&Ps[wave][l16][ks * 32 + quad * 8];
            #pragma unroll
            for (int dt = 0; dt < 4; ++dt) {
                s8 bv = *(const s8*)&Vt[dt * 16 + l16][ks * 32 + quad * 8];
                o[dt] = __builtin_amdgcn_mfma_f32_16x16x32_bf16(a, bv, o[dt], 0, 0, 0);
            }
        }
    }
    // epilogue
    #pragma unroll
    for (int reg = 0; reg < 4; ++reg) {
        const int t = t0 + wave * 16 + quad * 4 + reg;
        const float inv = 1.f / l_i[reg];
        #pragma unroll
        for (int dt = 0; dt < 4; ++dt) {
            size_t idx = (size_t)(b * T_ + t) * C_ + h * HD_ + dt * 16 + l16;
            float v = o[dt][reg] * inv;
            if constexpr (MODE == 0) outbuf[idx] += v;
            else                     outbuf[idx] = v;
        }
    }
}

// ---------------- gating elementwise ----------------
__global__ __launch_bounds__(256) void gate_kernel(
    const float* __restrict__ gs_lin, const float* __restrict__ gc_lin,
    const float* __restrict__ cval, const float* __restrict__ sval,
    float* __restrict__ gated)
{
    int i = blockIdx.x * 256 + threadIdx.x;
    float sg = 1.f / (1.f + __expf(-gs_lin[i]));
    float cg = 1.f / (1.f + __expf(-gc_lin[i]));
    gated[i] = sg * cval[i] + cg * sval[i];
}

extern "C" void kernel_launch(void* const* d_in, const int* in_sizes, int n_in,
                              void* d_out, int out_size, void* d_ws, size_t ws_size,
                              hipStream_t stream)
{
    const float* x      = (const float*)d_in[0];
    const float* y      = (const float*)d_in[1];
    // d_in[2]: attn_x_mask — structurally causal tril, computed inline
    const float* Wqkv_x = (const float*)d_in[3];
    const float* bqkv_x = (const float*)d_in[4];
    const float* Wqkv_y = (const float*)d_in[5];
    const float* bqkv_y = (const float*)d_in[6];
    const float* w4x    = (const float*)d_in[7];
    const float* w4y    = (const float*)d_in[8];
    const float* w4xy   = (const float*)d_in[9];
    const float* Wgs    = (const float*)d_in[10];
    const float* bgs    = (const float*)d_in[11];
    const float* Wgc    = (const float*)d_in[12];
    const float* bgc    = (const float*)d_in[13];
    const float* Wp     = (const float*)d_in[14];
    const float* bp     = (const float*)d_in[15];

    float* ws = (float*)d_ws;
    float* qkv_x  = ws;                 //  6,291,456 f
    float* qkv_y  = ws +  6291456;      //  1,572,864 f
    float* catt   = ws +  7864320;      //  8,388,608 f (raw logits -> x2y fp32 in place)
    bf16*  x2y_bf = (bf16*)(ws + 16252928);  // 8,388,608 bf16 (4,194,304 f-slots)
    bf16*  y2x_bf = (bf16*)(ws + 20447232);  // 8,388,608 bf16
    float* cval   = ws + 24641536;      //  2,097,152 f
    float* sval   = ws + 26738688;      //  2,097,152 f
    float* catt1b = ws + 28835840;      //  32,768 f
    float* catt2b = ws + 28868608;      //   8,192 f
    float* colmax = ws + 28876800;      //   8,192 f
    float* colinv = ws + 28884992;      //   8,192 f  (end 28,893,184 f = 115.6 MB)
    float* pmax_  = cval;               // reuse: cval written later (after colfin)
    float* psum_  = cval + 131072;
    float* gs_lin = qkv_x;              // reuse: qkv_x dead after flash<1>
    float* gc_lin = qkv_x + 2097152;
    float* gated  = qkv_x + 4194304;

    // 1-2: QKV projections
    gemm_bias_kernel<float><<<dim3(24, 64), 256, 0, stream>>>(x, Wqkv_x, bqkv_x, qkv_x, C3_, C_);
    gemm_bias_kernel<float><<<dim3(24, 16), 256, 0, stream>>>(y, Wqkv_y, bqkv_y, qkv_y, C3_, C_);

    // 3-5: attention logits catt (B,H,T,M)
    catt12_kernel<<<128, 256, 0, stream>>>(qkv_x, w4x, catt1b, T_);
    catt12_kernel<<<32, 256, 0, stream>>>(qkv_y, w4y, catt2b, M_);
    catt3_kernel<<<dim3(4, 16, 32), 256, 0, stream>>>(qkv_x, qkv_y, w4xy, catt1b, catt2b, catt);

    // 6: column softmax (over t) -> y2x bf16, parallelized 3-stage
    colpart_kernel<<<dim3(16, 32), 256, 0, stream>>>(catt, pmax_, psum_);
    colfin_kernel<<<32, 256, 0, stream>>>(pmax_, psum_, colmax, colinv);
    y2x_write_kernel<<<dim3(16, 32), 256, 0, stream>>>(catt, colmax, colinv, y2x_bf);

    // 7: row softmax (over m), in place fp32 + bf16 copy
    row_softmax_kernel<<<32768, 256, 0, stream>>>(catt, x2y_bf);

    // 8: cval = x + x2y @ v_y
    cval_x2y_kernel<<<dim3(16, 32), 256, 0, stream>>>(catt, qkv_y, x, cval);

    // 9: cval += softmax(causal(x2y @ y2x^T / 16)) @ v_x   [MFMA]
    flash_mfma_kernel<0><<<dim3(16, 32), 256, 0, stream>>>(x2y_bf, y2x_bf, qkv_x, 1.f / 16.f, cval);

    // 10: sval = causal self-attention(q_x, k_x, v_x)      [MFMA]
    flash_mfma_kernel<1><<<dim3(16, 32), 256, 0, stream>>>(nullptr, nullptr, qkv_x, 0.125f, sval);

    // 11-14: gates and output projection
    gemm_bias_kernel<float><<<dim3(8, 64), 256, 0, stream>>>(sval, Wgs, bgs, gs_lin, C_, C_);
    gemm_bias_kernel<float><<<dim3(8, 64), 256, 0, stream>>>(cval, Wgc, bgc, gc_lin, C_, C_);
    gate_kernel<<<8192, 256, 0, stream>>>(gs_lin, gc_lin, cval, sval, gated);
    gemm_bias_kernel<float><<<dim3(8, 64), 256, 0, stream>>>(gated, Wp, bp, (float*)d_out, C_, C_);
}

// Round 6
// 496.716 us; speedup vs baseline: 3.5269x; 1.4165x over previous
//
#include <hip/hip_runtime.h>
#include <hip/hip_bf16.h>

typedef __hip_bfloat16 bf16;
using f4 = __attribute__((ext_vector_type(4))) float;
using s8 = __attribute__((ext_vector_type(8))) short;

__device__ __forceinline__ void storeOut(float* p, float v) { *p = v; }
__device__ __forceinline__ void storeOut(bf16* p, float v) { *p = __float2bfloat16(v); }
__device__ __forceinline__ short bfs(float x) { return __builtin_bit_cast(short, __float2bfloat16(x)); }
__device__ __forceinline__ void pack8(short* dst, const float* sp) {
    s8 r;
    #pragma unroll
    for (int j = 0; j < 8; ++j) r[j] = bfs(sp[j]);
    *(s8*)dst = r;
}

constexpr int B_ = 4, T_ = 1024, M_ = 256, C_ = 512, H_ = 8, HD_ = 64, C3_ = 1536;

// ---------------- weight transpose + bf16 cast: W(K x N) -> WT(N x K) ----------------
__global__ __launch_bounds__(256) void transpose_w_kernel(
    const float* __restrict__ W, bf16* __restrict__ WT, int N, int K)
{
    __shared__ float Ls[64][65];
    const int tid = threadIdx.x;
    const int n0 = blockIdx.x * 64, k0 = blockIdx.y * 64;
    for (int t = tid; t < 1024; t += 256) {
        int kr = t >> 4, ng = t & 15;
        float4 v = *(const float4*)&W[(size_t)(k0 + kr) * N + n0 + ng * 4];
        Ls[ng * 4 + 0][kr] = v.x; Ls[ng * 4 + 1][kr] = v.y;
        Ls[ng * 4 + 2][kr] = v.z; Ls[ng * 4 + 3][kr] = v.w;
    }
    __syncthreads();
    for (int t = tid; t < 512; t += 256) {
        int n = t >> 3, kg = t & 7;
        s8 r;
        #pragma unroll
        for (int j = 0; j < 8; ++j) r[j] = bfs(Ls[n][kg * 8 + j]);
        *(s8*)&WT[(size_t)(n0 + n) * K + k0 + kg * 8] = r;
    }
}

// ---------------- MFMA GEMM: C = A(Mx K, fp32) @ WT^T (WT: N x K bf16) + bias ----------------
// 128x64 tile, BK=64, 4 waves; wave = 2x4 tiles of 16x16 (32 rows x 64 cols).
// Fragment layouts as verified in flash_mfma (R5): A/B frag idx=lane&15,k=quad*8+j;
// C/D col=lane&15,row=quad*4+reg.
template <typename OT>
__global__ __launch_bounds__(256) void mfma_gemm_kernel(
    const float* __restrict__ A, const bf16* __restrict__ WT, const float* __restrict__ bias,
    OT* __restrict__ Cmat, int N, int K)
{
    __shared__ short Asb[128][72];
    __shared__ short Bsb[64][72];
    const int tid = threadIdx.x;
    const int wave = tid >> 6, lane = tid & 63;
    const int quad = lane >> 4, l16 = lane & 15;
    const int n0 = blockIdx.x * 64, m0 = blockIdx.y * 128;
    f4 acc[2][4];
    #pragma unroll
    for (int mt = 0; mt < 2; ++mt)
        #pragma unroll
        for (int nt = 0; nt < 4; ++nt) acc[mt][nt] = (f4)0.f;

    for (int k0 = 0; k0 < K; k0 += 64) {
        for (int t = tid; t < 1024; t += 256) {
            int row = t >> 3, cg = t & 7;
            pack8(&Asb[row][cg * 8], &A[(size_t)(m0 + row) * K + k0 + cg * 8]);
        }
        for (int t = tid; t < 512; t += 256) {
            int n = t >> 3, cg = t & 7;
            *(s8*)&Bsb[n][cg * 8] = *(const s8*)&WT[(size_t)(n0 + n) * K + k0 + cg * 8];
        }
        __syncthreads();
        #pragma unroll
        for (int ks = 0; ks < 2; ++ks) {
            s8 a0 = *(const s8*)&Asb[wave * 32 + l16][ks * 32 + quad * 8];
            s8 a1 = *(const s8*)&Asb[wave * 32 + 16 + l16][ks * 32 + quad * 8];
            #pragma unroll
            for (int nt = 0; nt < 4; ++nt) {
                s8 bv = *(const s8*)&Bsb[nt * 16 + l16][ks * 32 + quad * 8];
                acc[0][nt] = __builtin_amdgcn_mfma_f32_16x16x32_bf16(a0, bv, acc[0][nt], 0, 0, 0);
                acc[1][nt] = __builtin_amdgcn_mfma_f32_16x16x32_bf16(a1, bv, acc[1][nt], 0, 0, 0);
            }
        }
        __syncthreads();
    }
    #pragma unroll
    for (int mt = 0; mt < 2; ++mt)
        #pragma unroll
        for (int nt = 0; nt < 4; ++nt) {
            int col = n0 + nt * 16 + l16;
            float bb = bias[col];
            #pragma unroll
            for (int reg = 0; reg < 4; ++reg) {
                int row = m0 + wave * 32 + mt * 16 + quad * 4 + reg;
                storeOut(&Cmat[(size_t)row * N + col], acc[mt][nt][reg] + bb);
            }
        }
}

// ---------------- catt1 / catt2 ----------------
__global__ __launch_bounds__(256) void catt12_kernel(
    const float* __restrict__ qkv, const float* __restrict__ w4,
    float* __restrict__ out, int Nrows)
{
    int i = blockIdx.x * 256 + threadIdx.x;
    int bh = i / Nrows, t = i - bh * Nrows;
    int b = bh >> 3, h = bh & 7;
    const float* row = qkv + (size_t)(b * Nrows + t) * C3_ + h * HD_;
    const float* w = w4 + h * HD_;
    float s = 0.f;
    #pragma unroll
    for (int d = 0; d < HD_; ++d) s = fmaf(row[d], w[d], s);
    out[i] = s;
}

// ---------------- catt = catt1 + catt2 + 0.125 * (qx*w4xy) @ ky^T ----------------
__global__ __launch_bounds__(256) void catt3_kernel(
    const float* __restrict__ qkv_x, const float* __restrict__ qkv_y,
    const float* __restrict__ w4xy, const float* __restrict__ catt1,
    const float* __restrict__ catt2, float* __restrict__ catt)
{
    __shared__ float As[64][68];
    __shared__ float Bs[64][65];
    __shared__ float w4s[64];
    const int tid = threadIdx.x;
    const int bh = blockIdx.z, b = bh >> 3, h = bh & 7;
    const int t0 = blockIdx.y * 64, m0 = blockIdx.x * 64;
    if (tid < 64) w4s[tid] = w4xy[h * HD_ + tid];
    __syncthreads();
    for (int idx = tid; idx < 4096; idx += 256) {
        int rr = idx >> 6, dd = idx & 63;
        As[rr][dd] = qkv_x[(size_t)(b * T_ + t0 + rr) * C3_ + h * HD_ + dd] * w4s[dd];
        Bs[dd][rr] = qkv_y[(size_t)(b * M_ + m0 + rr) * C3_ + C_ + h * HD_ + dd];
    }
    __syncthreads();
    const int tx = tid & 15, ty = tid >> 4;
    float acc[4][4] = {};
    for (int d = 0; d < 64; ++d) {
        float a[4], bb[4];
        #pragma unroll
        for (int i = 0; i < 4; ++i) a[i] = As[ty * 4 + i][d];
        #pragma unroll
        for (int j = 0; j < 4; ++j) bb[j] = Bs[d][tx * 4 + j];
        #pragma unroll
        for (int i = 0; i < 4; ++i)
            #pragma unroll
            for (int j = 0; j < 4; ++j)
                acc[i][j] = fmaf(a[i], bb[j], acc[i][j]);
    }
    #pragma unroll
    for (int i = 0; i < 4; ++i) {
        int t = t0 + ty * 4 + i;
        float c1 = catt1[bh * T_ + t];
        #pragma unroll
        for (int j = 0; j < 4; ++j) {
            int m = m0 + tx * 4 + j;
            catt[((size_t)bh * T_ + t) * M_ + m] = acc[i][j] * 0.125f + c1 + catt2[bh * M_ + m];
        }
    }
}

// ---------------- col softmax stage 1 ----------------
__global__ __launch_bounds__(256) void colpart_kernel(
    const float* __restrict__ catt, float* __restrict__ pmax, float* __restrict__ psum)
{
    const int ch = blockIdx.x, bh = blockIdx.y, m = threadIdx.x;
    const float* p = catt + ((size_t)bh * T_ + ch * 64) * M_ + m;
    float mx = -3e38f, s = 0.f;
    for (int t = 0; t < 64; ++t) {
        float v = p[t * M_];
        if (v > mx) { s = s * __expf(mx - v) + 1.f; mx = v; }
        else s += __expf(v - mx);
    }
    pmax[(bh * 16 + ch) * M_ + m] = mx;
    psum[(bh * 16 + ch) * M_ + m] = s;
}

// ---------------- col softmax stage 2 ----------------
__global__ __launch_bounds__(256) void colfin_kernel(
    const float* __restrict__ pmax, const float* __restrict__ psum,
    float* __restrict__ colmax, float* __restrict__ colinv)
{
    const int bh = blockIdx.x, m = threadIdx.x;
    float mx = -3e38f;
    #pragma unroll
    for (int ch = 0; ch < 16; ++ch) mx = fmaxf(mx, pmax[(bh * 16 + ch) * M_ + m]);
    float s = 0.f;
    #pragma unroll
    for (int ch = 0; ch < 16; ++ch)
        s += psum[(bh * 16 + ch) * M_ + m] * __expf(pmax[(bh * 16 + ch) * M_ + m] - mx);
    colmax[bh * M_ + m] = mx;
    colinv[bh * M_ + m] = 1.f / s;
}

// ---------------- col softmax stage 3: write y2x bf16 ----------------
__global__ __launch_bounds__(256) void y2x_write_kernel(
    const float* __restrict__ catt, const float* __restrict__ colmax,
    const float* __restrict__ colinv, bf16* __restrict__ y2x)
{
    const int ch = blockIdx.x, bh = blockIdx.y, m = threadIdx.x;
    const float mx = colmax[bh * M_ + m], inv = colinv[bh * M_ + m];
    const size_t base = ((size_t)bh * T_ + ch * 64) * M_ + m;
    for (int t = 0; t < 64; ++t)
        y2x[base + t * M_] = __float2bfloat16(__expf(catt[base + t * M_] - mx) * inv);
}

// ---------------- row softmax -> x2y bf16 ----------------
__global__ __launch_bounds__(256) void row_softmax_kernel(
    const float* __restrict__ catt, bf16* __restrict__ x2y_bf)
{
    const int row = blockIdx.x;
    const int tid = threadIdx.x;
    float v = catt[(size_t)row * M_ + tid];
    float mx = v;
    for (int off = 1; off < 64; off <<= 1) mx = fmaxf(mx, __shfl_xor(mx, off));
    __shared__ float red[4], red2[4];
    if ((tid & 63) == 0) red[tid >> 6] = mx;
    __syncthreads();
    mx = fmaxf(fmaxf(red[0], red[1]), fmaxf(red[2], red[3]));
    float e = __expf(v - mx);
    float s = e;
    for (int off = 1; off < 64; off <<= 1) s += __shfl_xor(s, off);
    if ((tid & 63) == 0) red2[tid >> 6] = s;
    __syncthreads();
    s = red2[0] + red2[1] + red2[2] + red2[3];
    x2y_bf[(size_t)row * M_ + tid] = __float2bfloat16(e / s);
}

// ---------------- cval = x + x2y @ v_y  [MFMA, flash-pattern minus softmax] ----------------
__global__ __launch_bounds__(256) void cval_mfma_kernel(
    const bf16* __restrict__ x2y_bf, const float* __restrict__ qkv_y,
    const float* __restrict__ x, float* __restrict__ cval)
{
    __shared__ short Psb[64][72];
    __shared__ short Vt[64][72];   // v_y transposed [d][m]
    const int tid = threadIdx.x;
    const int wave = tid >> 6, lane = tid & 63;
    const int quad = lane >> 4, l16 = lane & 15;
    const int bh = blockIdx.y, b = bh >> 3, h = bh & 7;
    const int t0 = blockIdx.x * 64;
    f4 o[4];
    #pragma unroll
    for (int dt = 0; dt < 4; ++dt) o[dt] = (f4)0.f;

    for (int kc = 0; kc < 4; ++kc) {
        if (kc > 0) __syncthreads();
        for (int t = tid; t < 512; t += 256) {
            int row = t >> 3, cg = t & 7;
            *(s8*)&Psb[row][cg * 8] =
                *(const s8*)&x2y_bf[((size_t)bh * T_ + t0 + row) * M_ + kc * 64 + cg * 8];
        }
        {
            int s = tid >> 4, d4 = (tid & 15) * 4;
            #pragma unroll
            for (int it = 0; it < 4; ++it, s += 16) {
                float4 v = *(const float4*)&qkv_y[(size_t)(b * M_ + kc * 64 + s) * C3_ + 2 * C_ + h * HD_ + d4];
                Vt[d4 + 0][s] = bfs(v.x); Vt[d4 + 1][s] = bfs(v.y);
                Vt[d4 + 2][s] = bfs(v.z); Vt[d4 + 3][s] = bfs(v.w);
            }
        }
        __syncthreads();
        #pragma unroll
        for (int ks = 0; ks < 2; ++ks) {
            s8 a = *(const s8*)&Psb[wave * 16 + l16][ks * 32 + quad * 8];
            #pragma unroll
            for (int dt = 0; dt < 4; ++dt) {
                s8 bv = *(const s8*)&Vt[dt * 16 + l16][ks * 32 + quad * 8];
                o[dt] = __builtin_amdgcn_mfma_f32_16x16x32_bf16(a, bv, o[dt], 0, 0, 0);
            }
        }
    }
    #pragma unroll
    for (int reg = 0; reg < 4; ++reg) {
        const int t = t0 + wave * 16 + quad * 4 + reg;
        #pragma unroll
        for (int dt = 0; dt < 4; ++dt) {
            size_t idx = (size_t)(b * T_ + t) * C_ + h * HD_ + dt * 16 + l16;
            cval[idx] = o[dt][reg] + x[idx];
        }
    }
}

// ---------------- MFMA flash attention (causal, online softmax) ----------------
template <int MODE>
__global__ __launch_bounds__(256) void flash_mfma_kernel(
    const bf16* __restrict__ Qsrc, const bf16* __restrict__ Ksrc,
    const float* __restrict__ qkv_x, float scale, float* __restrict__ outbuf)
{
    constexpr int DK = (MODE == 0) ? 256 : 64;
    constexpr int NCH = DK / 64;
    __shared__ short Qs[64][DK + 8];
    __shared__ short Ks[64][72];
    __shared__ short Vt[64][72];
    __shared__ short Ps[4][16][72];
    const int tid = threadIdx.x;
    const int wave = tid >> 6, lane = tid & 63;
    const int quad = lane >> 4, l16 = lane & 15;
    const int bh = blockIdx.y, b = bh >> 3, h = bh & 7;
    const int t0 = blockIdx.x * 64;

    for (int i = tid; i < 64 * (DK / 8); i += 256) {
        int row = i / (DK / 8), cg = i % (DK / 8);
        if constexpr (MODE == 0)
            *(s8*)&Qs[row][cg * 8] = *(const s8*)&Qsrc[((size_t)bh * T_ + t0 + row) * M_ + cg * 8];
        else
            pack8(&Qs[row][cg * 8], &qkv_x[(size_t)(b * T_ + t0 + row) * C3_ + h * HD_ + cg * 8]);
    }

    float m_i[4], l_i[4];
    f4 o[4];
    #pragma unroll
    for (int r = 0; r < 4; ++r) { m_i[r] = -3e38f; l_i[r] = 0.f; o[r] = (f4)0.f; }

    const int nst = blockIdx.x + 1;
    for (int st = 0; st < nst; ++st) {
        const int s0 = st * 64;
        __syncthreads();
        {
            int s = tid >> 4, d4 = (tid & 15) * 4;
            #pragma unroll
            for (int it = 0; it < 4; ++it, s += 16) {
                float4 v = *(const float4*)&qkv_x[(size_t)(b * T_ + s0 + s) * C3_ + 2 * C_ + h * HD_ + d4];
                Vt[d4 + 0][s] = bfs(v.x); Vt[d4 + 1][s] = bfs(v.y);
                Vt[d4 + 2][s] = bfs(v.z); Vt[d4 + 3][s] = bfs(v.w);
            }
        }
        f4 sc[4];
        #pragma unroll
        for (int nt = 0; nt < 4; ++nt) sc[nt] = (f4)0.f;
        for (int kc = 0; kc < NCH; ++kc) {
            if (kc > 0) __syncthreads();
            for (int i = tid; i < 512; i += 256) {
                int key = i >> 3, cg = i & 7;
                if constexpr (MODE == 0)
                    *(s8*)&Ks[key][cg * 8] =
                        *(const s8*)&Ksrc[((size_t)bh * T_ + s0 + key) * M_ + kc * 64 + cg * 8];
                else
                    pack8(&Ks[key][cg * 8],
                          &qkv_x[(size_t)(b * T_ + s0 + key) * C3_ + C_ + h * HD_ + cg * 8]);
            }
            __syncthreads();
            #pragma unroll
            for (int ks = 0; ks < 2; ++ks) {
                s8 a = *(const s8*)&Qs[wave * 16 + l16][kc * 64 + ks * 32 + quad * 8];
                #pragma unroll
                for (int nt = 0; nt < 4; ++nt) {
                    s8 bf = *(const s8*)&Ks[nt * 16 + l16][ks * 32 + quad * 8];
                    sc[nt] = __builtin_amdgcn_mfma_f32_16x16x32_bf16(a, bf, sc[nt], 0, 0, 0);
                }
            }
        }
        #pragma unroll
        for (int reg = 0; reg < 4; ++reg) {
            const int t_g = t0 + wave * 16 + quad * 4 + reg;
            float mx = -3e38f;
            #pragma unroll
            for (int nt = 0; nt < 4; ++nt) {
                float v = (s0 + nt * 16 + l16 <= t_g) ? sc[nt][reg] * scale : -3e38f;
                sc[nt][reg] = v;
                mx = fmaxf(mx, v);
            }
            mx = fmaxf(mx, __shfl_xor(mx, 1));
            mx = fmaxf(mx, __shfl_xor(mx, 2));
            mx = fmaxf(mx, __shfl_xor(mx, 4));
            mx = fmaxf(mx, __shfl_xor(mx, 8));
            float mnew = fmaxf(m_i[reg], mx);
            float sum = 0.f;
            #pragma unroll
            for (int nt = 0; nt < 4; ++nt) {
                float p = __expf(sc[nt][reg] - mnew);
                sc[nt][reg] = p;
                sum += p;
            }
            sum += __shfl_xor(sum, 1);
            sum += __shfl_xor(sum, 2);
            sum += __shfl_xor(sum, 4);
            sum += __shfl_xor(sum, 8);
            float alpha = __expf(m_i[reg] - mnew);
            l_i[reg] = l_i[reg] * alpha + sum;
            m_i[reg] = mnew;
            #pragma unroll
            for (int dt = 0; dt < 4; ++dt) o[dt][reg] *= alpha;
            #pragma unroll
            for (int nt = 0; nt < 4; ++nt)
                Ps[wave][quad * 4 + reg][nt * 16 + l16] = bfs(sc[nt][reg]);
        }
        #pragma unroll
        for (int ks = 0; ks < 2; ++ks) {
            s8 a = *(const s8*)&Ps[wave][l16][ks * 32 + quad * 8];
            #pragma unroll
            for (int dt = 0; dt < 4; ++dt) {
                s8 bv = *(const s8*)&Vt[dt * 16 + l16][ks * 32 + quad * 8];
                o[dt] = __builtin_amdgcn_mfma_f32_16x16x32_bf16(a, bv, o[dt], 0, 0, 0);
            }
        }
    }
    #pragma unroll
    for (int reg = 0; reg < 4; ++reg) {
        const int t = t0 + wave * 16 + quad * 4 + reg;
        const float inv = 1.f / l_i[reg];
        #pragma unroll
        for (int dt = 0; dt < 4; ++dt) {
            size_t idx = (size_t)(b * T_ + t) * C_ + h * HD_ + dt * 16 + l16;
            float v = o[dt][reg] * inv;
            if constexpr (MODE == 0) outbuf[idx] += v;
            else                     outbuf[idx] = v;
        }
    }
}

// ---------------- gating elementwise ----------------
__global__ __launch_bounds__(256) void gate_kernel(
    const float* __restrict__ gs_lin, const float* __restrict__ gc_lin,
    const float* __restrict__ cval, const float* __restrict__ sval,
    float* __restrict__ gated)
{
    int i = blockIdx.x * 256 + threadIdx.x;
    float sg = 1.f / (1.f + __expf(-gs_lin[i]));
    float cg = 1.f / (1.f + __expf(-gc_lin[i]));
    gated[i] = sg * cval[i] + cg * sval[i];
}

extern "C" void kernel_launch(void* const* d_in, const int* in_sizes, int n_in,
                              void* d_out, int out_size, void* d_ws, size_t ws_size,
                              hipStream_t stream)
{
    const float* x      = (const float*)d_in[0];
    const float* y      = (const float*)d_in[1];
    // d_in[2]: attn_x_mask — structurally causal tril, computed inline
    const float* Wqkv_x = (const float*)d_in[3];
    const float* bqkv_x = (const float*)d_in[4];
    const float* Wqkv_y = (const float*)d_in[5];
    const float* bqkv_y = (const float*)d_in[6];
    const float* w4x    = (const float*)d_in[7];
    const float* w4y    = (const float*)d_in[8];
    const float* w4xy   = (const float*)d_in[9];
    const float* Wgs    = (const float*)d_in[10];
    const float* bgs    = (const float*)d_in[11];
    const float* Wgc    = (const float*)d_in[12];
    const float* bgc    = (const float*)d_in[13];
    const float* Wp     = (const float*)d_in[14];
    const float* bp     = (const float*)d_in[15];

    float* ws = (float*)d_ws;
    float* qkv_x  = ws;                 //  6,291,456 f
    float* qkv_y  = ws +  6291456;      //  1,572,864 f
    float* catt   = ws +  7864320;      //  8,388,608 f (raw logits)
    bf16*  x2y_bf = (bf16*)(ws + 16252928);  // 8,388,608 bf16
    bf16*  y2x_bf = (bf16*)(ws + 20447232);  // 8,388,608 bf16
    float* cval   = ws + 24641536;      //  2,097,152 f
    float* sval   = ws + 26738688;      //  2,097,152 f
    float* catt1b = ws + 28835840;      //  32,768 f
    float* catt2b = ws + 28868608;      //   8,192 f
    float* colmax = ws + 28876800;      //   8,192 f
    float* colinv = ws + 28884992;      //   8,192 f
    float* pmax_  = cval;               // reuse: cval written later
    float* psum_  = cval + 131072;
    float* gs_lin = qkv_x;              // reuse: qkv_x dead after flash<1>
    float* gc_lin = qkv_x + 2097152;
    float* gated  = qkv_x + 4194304;
    // WT buffers overlap x2y/y2x regions (disjoint lifetimes):
    bf16* WT_x  = x2y_bf;               // 786,432 el; dead before row_softmax writes x2y
    bf16* WT_y  = x2y_bf + 786432;      // 786,432 el
    bf16* WT_gs = y2x_bf;               // 262,144 el; written after flash<0> reads y2x
    bf16* WT_gc = y2x_bf + 262144;
    bf16* WT_p  = y2x_bf + 524288;

    // 0: weight transposes (fp32 K x N -> bf16 N x K)
    transpose_w_kernel<<<dim3(24, 8), 256, 0, stream>>>(Wqkv_x, WT_x, C3_, C_);
    transpose_w_kernel<<<dim3(24, 8), 256, 0, stream>>>(Wqkv_y, WT_y, C3_, C_);

    // 1-2: QKV projections [MFMA]
    mfma_gemm_kernel<float><<<dim3(24, 32), 256, 0, stream>>>(x, WT_x, bqkv_x, qkv_x, C3_, C_);
    mfma_gemm_kernel<float><<<dim3(24, 8), 256, 0, stream>>>(y, WT_y, bqkv_y, qkv_y, C3_, C_);

    // 3-5: attention logits catt (B,H,T,M)
    catt12_kernel<<<128, 256, 0, stream>>>(qkv_x, w4x, catt1b, T_);
    catt12_kernel<<<32, 256, 0, stream>>>(qkv_y, w4y, catt2b, M_);
    catt3_kernel<<<dim3(4, 16, 32), 256, 0, stream>>>(qkv_x, qkv_y, w4xy, catt1b, catt2b, catt);

    // 6: column softmax (over t) -> y2x bf16
    colpart_kernel<<<dim3(16, 32), 256, 0, stream>>>(catt, pmax_, psum_);
    colfin_kernel<<<32, 256, 0, stream>>>(pmax_, psum_, colmax, colinv);
    y2x_write_kernel<<<dim3(16, 32), 256, 0, stream>>>(catt, colmax, colinv, y2x_bf);

    // 7: row softmax (over m) -> x2y bf16
    row_softmax_kernel<<<32768, 256, 0, stream>>>(catt, x2y_bf);

    // 8: cval = x + x2y @ v_y [MFMA]
    cval_mfma_kernel<<<dim3(16, 32), 256, 0, stream>>>(x2y_bf, qkv_y, x, cval);

    // 9: cval += softmax(causal(x2y @ y2x^T / 16)) @ v_x [MFMA]
    flash_mfma_kernel<0><<<dim3(16, 32), 256, 0, stream>>>(x2y_bf, y2x_bf, qkv_x, 1.f / 16.f, cval);

    // 9b: gate/output weight transposes (y2x region now dead)
    transpose_w_kernel<<<dim3(8, 8), 256, 0, stream>>>(Wgs, WT_gs, C_, C_);
    transpose_w_kernel<<<dim3(8, 8), 256, 0, stream>>>(Wgc, WT_gc, C_, C_);
    transpose_w_kernel<<<dim3(8, 8), 256, 0, stream>>>(Wp, WT_p, C_, C_);

    // 10: sval = causal self-attention(q_x, k_x, v_x) [MFMA]
    flash_mfma_kernel<1><<<dim3(16, 32), 256, 0, stream>>>(nullptr, nullptr, qkv_x, 0.125f, sval);

    // 11-14: gates and output projection [MFMA]
    mfma_gemm_kernel<float><<<dim3(8, 32), 256, 0, stream>>>(sval, WT_gs, bgs, gs_lin, C_, C_);
    mfma_gemm_kernel<float><<<dim3(8, 32), 256, 0, stream>>>(cval, WT_gc, bgc, gc_lin, C_, C_);
    gate_kernel<<<8192, 256, 0, stream>>>(gs_lin, gc_lin, cval, sval, gated);
    mfma_gemm_kernel<float><<<dim3(8, 32), 256, 0, stream>>>(gated, WT_p, bp, (float*)d_out, C_, C_);
}